// Round 2
// baseline (293.044 us; speedup 1.0000x reference)
//
#include <hip/hip_runtime.h>
#include <math.h>

#define S_LEN 2048
#define NH 16
#define HD 64
#define DMODEL 1024
#define BATCH 4
#define M_TOT (BATCH * S_LEN)   // 8192

typedef __attribute__((ext_vector_type(8))) short bf16x8;
typedef __attribute__((ext_vector_type(4))) float f32x4;

#define CK 0.18033688f   // (1/sqrt(64)) * log2(e), folded into Q at projection

__device__ __forceinline__ unsigned short f2bf_rne(float f) {
    unsigned u = __float_as_uint(f);
    u += 0x7fffu + ((u >> 16) & 1u);
    return (unsigned short)(u >> 16);
}

__device__ __forceinline__ void gld16(unsigned short* lds, const unsigned short* g) {
    __builtin_amdgcn_global_load_lds(
        (const __attribute__((address_space(1))) void*)g,
        (__attribute__((address_space(3))) void*)lds, 16, 0, 0);
}

// ---------------------------------------------------------------------------
// cvt_fused: one dispatch for all input conversion.
// z=0..2: Wq/Wk/Wv [k][n] fp32 -> WT [n][k] bf16 (64x64 transpose tiles)
// z=3:    Wf (1024x64) -> WfT [64][1024]   (only blockIdx.x==0 active)
// z=4:    x fp32 -> bf16 (256 blocks x 32 float4/thread)
// ---------------------------------------------------------------------------
__global__ __launch_bounds__(256) void cvt_fused(
    const float* __restrict__ x,
    const float* __restrict__ Wq, const float* __restrict__ Wk,
    const float* __restrict__ Wv, const float* __restrict__ Wf,
    unsigned short* __restrict__ xb, unsigned short* __restrict__ WT)
{
    const int z = blockIdx.z;
    const int tid = threadIdx.x;

    if (z < 4) {
        if (z == 3 && blockIdx.x > 0) return;
        const float* W = (z == 0) ? Wq : (z == 1) ? Wk : (z == 2) ? Wv : Wf;
        const int ncol = (z == 3) ? 64 : DMODEL;
        unsigned short* out = WT + (size_t)z * DMODEL * DMODEL;

        __shared__ float Lt[64][65];
        const int r0 = blockIdx.y * 64;
        const int c0 = blockIdx.x * 64;

        #pragma unroll
        for (int p = 0; p < 4; p++) {
            int row = (tid >> 4) + p * 16;
            int c4 = (tid & 15) * 4;
            float4 v = *(const float4*)(W + (size_t)(r0 + row) * ncol + c0 + c4);
            Lt[row][c4 + 0] = v.x; Lt[row][c4 + 1] = v.y;
            Lt[row][c4 + 2] = v.z; Lt[row][c4 + 3] = v.w;
        }
        __syncthreads();
        #pragma unroll
        for (int p = 0; p < 4; p++) {
            int nr = (tid >> 4) + p * 16;
            int kc = (tid & 15) * 4;
            unsigned short t[4];
            #pragma unroll
            for (int j = 0; j < 4; j++) t[j] = f2bf_rne(Lt[kc + j][nr]);
            *(uint2*)(out + (size_t)(c0 + nr) * DMODEL + r0 + kc) = *(uint2*)t;
        }
    } else {
        const int gtid = (blockIdx.y * 16 + blockIdx.x) * 256 + tid;
        #pragma unroll
        for (int it = 0; it < 8; it++) {
            #pragma unroll
            for (int k = 0; k < 4; k++) {
                size_t i = ((size_t)((it * 4 + k) * 65536) + gtid) * 4;
                float4 v = *(const float4*)(x + i);
                unsigned short t[4];
                t[0] = f2bf_rne(v.x); t[1] = f2bf_rne(v.y);
                t[2] = f2bf_rne(v.z); t[3] = f2bf_rne(v.w);
                *(uint2*)(xb + i) = *(uint2*)t;
            }
        }
    }
}

// ---------------------------------------------------------------------------
// Kernel 1 (R14): QKV projection, bf16 MFMA 16x16x32.
//   Tile 256 rows x 128 oc, BK=64, 512 threads = 8 waves (4 row x 2 oc).
//   TRIPLE-BUFFERED LDS (144 KB, 1 block/CU) + COUNTED vmcnt pipeline (T3+T4):
//   at iter t the wave waits vmcnt(6) -- stage(t) complete, stage(t+1)'s 6
//   loads remain IN FLIGHT ACROSS the barrier -- then issues stage(t+2).
//   Loads get ~2 K-steps of latency cover (hides HBM-miss ~900cy).
//   R13 lesson: 2-phase dbuf with vmcnt(0)-drain barriers == no gain (m218:
//   the gain IS the counted vmcnt).  LDS chunk format, gld16 staging and
//   epilogue indexing are carried over unchanged from the verified R8 kernel.
// NOTE: do NOT add a min-waves launch_bounds (R10: VGPR 48 -> spill, 6x).
// ---------------------------------------------------------------------------
__global__ __launch_bounds__(512) void qkv_gemm_mfma(
    const unsigned short* __restrict__ xb,
    const unsigned short* __restrict__ WT,
    const float* __restrict__ bq, const float* __restrict__ bk,
    const float* __restrict__ bv,
    unsigned short* __restrict__ Qb, unsigned short* __restrict__ Kb,
    unsigned short* __restrict__ Vtb)
{
    // 3 pipeline stages: W-tile 128x64 (16 chunks of 1KB), x-tile 256x64 (32 chunks)
    __shared__ __align__(16) unsigned short As[3][16 * 512];   // 48 KB
    __shared__ __align__(16) unsigned short Bs[3][32 * 512];   // 96 KB

    // ---- XCD swizzle: 768 blocks, lin%8 = XCD (round-robin heuristic).
    // XCD k owns rb = 4k..4k+3 (1 MB x resident) for all (ocb,z).
    const int lin = blockIdx.x;          // 0..767
    const int xcd = lin & 7;
    const int s   = lin >> 3;            // 0..95
    const int rb  = xcd * 4 + (s & 3);   // 0..31  (256-row tiles)
    const int ocz = s >> 2;              // 0..23
    const int ocb = ocz & 7;             // 0..7   (128-oc tiles)
    const int z   = ocz >> 3;            // 0..2

    const unsigned short* Wz = WT + (size_t)z * DMODEL * DMODEL;
    const float* bias = (z == 0) ? bq : (z == 1) ? bk : bv;

    const int tid = threadIdx.x;
    const int lane = tid & 63, w = tid >> 6;        // w 0..7
    const int quad = lane >> 4, l15 = lane & 15;
    const int wq = w & 1;                           // oc half   (0..1)
    const int wr = w >> 1;                          // row quarter (0..3)

    const int OC0 = ocb * 128;
    const int R0  = rb * 256;

    // stage sources: wave w supplies oc-rows [w*16,w*16+16) of W and
    // x rows [w*16,..) and [(w+8)*16,..)
    const unsigned short* gA  = Wz + (size_t)(OC0 + w * 16 + l15) * DMODEL + quad * 8;
    const unsigned short* gB0 = xb + (size_t)(R0  + w * 16 + l15) * DMODEL + quad * 8;
    const unsigned short* gB1 = gB0 + (size_t)128 * DMODEL;

    f32x4 acc[4][4];
    #pragma unroll
    for (int i = 0; i < 4; i++)
        #pragma unroll
        for (int j = 0; j < 4; j++)
            #pragma unroll
            for (int c = 0; c < 4; c++) acc[i][j][c] = 0.f;

    // 6 gld16 per wave per stage: 2 for W-tile chunks, 4 for x-tile chunks
#define QKV_STAGE(At, Bt, K)  do {                                 \
        gld16((At) + (w * 2 + 0) * 512, gA  + (K));                \
        gld16((At) + (w * 2 + 1) * 512, gA  + (K) + 32);           \
        gld16((Bt) + (w * 2 + 0) * 512, gB0 + (K));                \
        gld16((Bt) + (w * 2 + 1) * 512, gB0 + (K) + 32);           \
        gld16((Bt) + ((w + 8) * 2 + 0) * 512, gB1 + (K));          \
        gld16((Bt) + ((w + 8) * 2 + 1) * 512, gB1 + (K) + 32);     \
    } while (0)

    // prologue: 2 tiles in flight (12 outstanding loads per wave)
    QKV_STAGE(As[0], Bs[0], 0);
    QKV_STAGE(As[1], Bs[1], 64);

    int cur = 0;
    for (int t = 0; t < 16; ++t) {
        // counted wait: stage(t) complete; stage(t+1) stays in flight.
        if (t < 15) asm volatile("s_waitcnt vmcnt(6)" ::: "memory");
        else        asm volatile("s_waitcnt vmcnt(0)" ::: "memory");
        __builtin_amdgcn_s_barrier();

        // issue stage(t+2) into the buffer computed at t-1 (all waves are
        // past its compute: they crossed this iteration's barrier).
        if (t <= 13) {
            int nb = cur + 2; if (nb >= 3) nb -= 3;
            QKV_STAGE(As[nb], Bs[nb], (t + 2) * 64);
        }

        const unsigned short* Ab = As[cur];
        const unsigned short* Bb = Bs[cur];

        __builtin_amdgcn_s_setprio(1);
        #pragma unroll
        for (int sl = 0; sl < 2; sl++) {
            bf16x8 af[4], bfr[4];
            #pragma unroll
            for (int i = 0; i < 4; i++)
                af[i]  = *(const bf16x8*)&Ab[((wq * 4 + i) * 2 + sl) * 512 + lane * 8];
            #pragma unroll
            for (int j = 0; j < 4; j++)
                bfr[j] = *(const bf16x8*)&Bb[((wr * 4 + j) * 2 + sl) * 512 + lane * 8];
            if (z != 2) {
                #pragma unroll
                for (int i = 0; i < 4; i++)
                    #pragma unroll
                    for (int j = 0; j < 4; j++)
                        acc[i][j] = __builtin_amdgcn_mfma_f32_16x16x32_bf16(
                            af[i], bfr[j], acc[i][j], 0, 0, 0);
            } else {
                #pragma unroll
                for (int i = 0; i < 4; i++)
                    #pragma unroll
                    for (int j = 0; j < 4; j++)
                        acc[i][j] = __builtin_amdgcn_mfma_f32_16x16x32_bf16(
                            bfr[j], af[i], acc[i][j], 0, 0, 0);
            }
        }
        __builtin_amdgcn_s_setprio(0);

        if (++cur == 3) cur = 0;
    }
#undef QKV_STAGE

    if (z != 2) {
        unsigned short* out = (z == 0) ? Qb : Kb;
        const float qs = (z == 0) ? CK : 1.0f;
        #pragma unroll
        for (int i = 0; i < 4; i++) {
            int oc = OC0 + wq * 64 + i * 16 + quad * 4;
            float4 bv4 = *(const float4*)&bias[oc];
            #pragma unroll
            for (int j = 0; j < 4; j++) {
                int row = R0 + wr * 64 + j * 16 + l15;
                unsigned short t4[4];
                t4[0] = f2bf_rne((acc[i][j][0] + bv4.x) * qs);
                t4[1] = f2bf_rne((acc[i][j][1] + bv4.y) * qs);
                t4[2] = f2bf_rne((acc[i][j][2] + bv4.z) * qs);
                t4[3] = f2bf_rne((acc[i][j][3] + bv4.w) * qs);
                *(uint2*)(out + (size_t)row * DMODEL + oc) = *(uint2*)t4;
            }
        }
    } else {
        const int b = R0 >> 11;                 // 256-row tiles never cross batch
        const int sbase = (R0 & 2047) + wr * 64;
        #pragma unroll
        for (int i = 0; i < 4; i++) {
            int oc = OC0 + wq * 64 + i * 16 + l15;
            float bvv = bias[oc];
            #pragma unroll
            for (int j = 0; j < 4; j++) {
                int sq = sbase + j * 16 + quad * 4;
                unsigned short t4[4];
                t4[0] = f2bf_rne(acc[i][j][0] + bvv);
                t4[1] = f2bf_rne(acc[i][j][1] + bvv);
                t4[2] = f2bf_rne(acc[i][j][2] + bvv);
                t4[3] = f2bf_rne(acc[i][j][3] + bvv);
                *(uint2*)(Vtb + (size_t)(b * DMODEL + oc) * S_LEN + sq) = *(uint2*)t4;
            }
        }
    }
}

// ---------------------------------------------------------------------------
// Kernel 2: flash attention — R8 structure (measured optimum) + XCD-AWARE
// SWIZZLE: all 16 q-tile blocks of one (b,h) map to the same XCD (bh%8), so
// that (b,h)'s K/V stream is fetched once per XCD instead of up to 8x.
// ---------------------------------------------------------------------------
__global__ __launch_bounds__(256, 4) void flash_attn_mfma(
    const unsigned short* __restrict__ Qg,   // [B*S,1024] bf16, pre-scaled by CK
    const unsigned short* __restrict__ Kg,   // [B*S,1024] bf16
    const unsigned short* __restrict__ Vtg,  // [B,H,64,S] bf16
    unsigned short* __restrict__ ctxb)       // [B*S,1024] bf16
{
    __shared__ __align__(16) unsigned short Ks[16 * 512];  // 16 KB
    __shared__ __align__(16) unsigned short Vs[16 * 512];  // 16 KB
    __shared__ __align__(16) unsigned short Ps[8 * 512];   //  8 KB

    const int tid  = threadIdx.x;
    const int lane = tid & 63, w = tid >> 6;
    const int quad = lane >> 4, l15 = lane & 15;

    // ---- XCD swizzle: lin -> (qblk, b, h) with bh%8 == lin%8 ----
    const int lin = blockIdx.x + 16 * (blockIdx.y + 16 * blockIdx.z);  // 0..1023
    const int xcd = lin & 7;
    const int s   = lin >> 3;              // 0..127
    const int bh  = xcd + 8 * (s >> 4);    // 0..63, bh%8 == xcd
    const int qblk = s & 15;
    const int b = bh >> 4, h = bh & 15;
    const int r0 = qblk * 128;

    bf16x8 qf[2][2];
    #pragma unroll
    for (int nt = 0; nt < 2; nt++)
        #pragma unroll
        for (int ds = 0; ds < 2; ds++)
            qf[nt][ds] = *(const bf16x8*)(Qg +
                (size_t)(b * S_LEN + r0 + w * 32 + nt * 16 + l15) * DMODEL +
                h * HD + ds * 32 + quad * 8);

    const unsigned short* gK = Kg + (size_t)(b * S_LEN + w * 16 + l15) * DMODEL + h * HD + quad * 8;
    const unsigned short* gV = Vtg + ((size_t)((b * NH + h) * HD + w * 16 + l15)) * S_LEN + quad * 8;

    f32x4 O[2][4], lsum[2];
    #pragma unroll
    for (int rt = 0; rt < 2; rt++) {
        #pragma unroll
        for (int c = 0; c < 4; c++) lsum[rt][c] = 0.f;
        #pragma unroll
        for (int dt = 0; dt < 4; dt++)
            #pragma unroll
            for (int c = 0; c < 4; c++) O[rt][dt][c] = 0.f;
    }

    f32x4 zero4;
    #pragma unroll
    for (int c = 0; c < 4; c++) zero4[c] = 0.f;
    bf16x8 ones;
    #pragma unroll
    for (int c = 0; c < 8; c++) ones[c] = (short)0x3F80;   // bf16 1.0

    for (int st = 0; st < S_LEN / 128; st++) {
        __syncthreads();
        gld16(Ks + ((w + 0) * 2 + 0) * 512, gK);
        gld16(Ks + ((w + 0) * 2 + 1) * 512, gK + 32);
        gld16(Ks + ((w + 4) * 2 + 0) * 512, gK + (size_t)64 * DMODEL);
        gld16(Ks + ((w + 4) * 2 + 1) * 512, gK + (size_t)64 * DMODEL + 32);
        gld16(Vs + (w * 4 + 0) * 512, gV);
        gld16(Vs + (w * 4 + 1) * 512, gV + 32);
        gld16(Vs + (w * 4 + 2) * 512, gV + 64);
        gld16(Vs + (w * 4 + 3) * 512, gV + 96);
        gK += (size_t)128 * DMODEL;
        gV += 128;
        __syncthreads();

        #pragma unroll
        for (int r = 0; r < 4; r++) {
            f32x4 sc[2][2];
            {
                bf16x8 kf0 = *(const bf16x8*)&Ks[((r * 2 + 0) * 2 + 0) * 512 + lane * 8];
                bf16x8 kf1 = *(const bf16x8*)&Ks[((r * 2 + 1) * 2 + 0) * 512 + lane * 8];
                sc[0][0] = __builtin_amdgcn_mfma_f32_16x16x32_bf16(kf0, qf[0][0], zero4, 0, 0, 0);
                sc[0][1] = __builtin_amdgcn_mfma_f32_16x16x32_bf16(kf0, qf[1][0], zero4, 0, 0, 0);
                sc[1][0] = __builtin_amdgcn_mfma_f32_16x16x32_bf16(kf1, qf[0][0], zero4, 0, 0, 0);
                sc[1][1] = __builtin_amdgcn_mfma_f32_16x16x32_bf16(kf1, qf[1][0], zero4, 0, 0, 0);
                kf0 = *(const bf16x8*)&Ks[((r * 2 + 0) * 2 + 1) * 512 + lane * 8];
                kf1 = *(const bf16x8*)&Ks[((r * 2 + 1) * 2 + 1) * 512 + lane * 8];
                sc[0][0] = __builtin_amdgcn_mfma_f32_16x16x32_bf16(kf0, qf[0][1], sc[0][0], 0, 0, 0);
                sc[0][1] = __builtin_amdgcn_mfma_f32_16x16x32_bf16(kf0, qf[1][1], sc[0][1], 0, 0, 0);
                sc[1][0] = __builtin_amdgcn_mfma_f32_16x16x32_bf16(kf1, qf[0][1], sc[1][0], 0, 0, 0);
                sc[1][1] = __builtin_amdgcn_mfma_f32_16x16x32_bf16(kf1, qf[1][1], sc[1][1], 0, 0, 0);
            }

            #pragma unroll
            for (int nt = 0; nt < 2; nt++) {
                #pragma unroll
                for (int mt = 0; mt < 2; mt++) {
                    unsigned u[4];
                    #pragma unroll
                    for (int c = 0; c < 4; c++)
                        u[c] = __float_as_uint(__builtin_amdgcn_exp2f(sc[mt][nt][c]));
                    uint2 pk;
                    pk.x = __builtin_amdgcn_perm(u[1], u[0], 0x07060302u);
                    pk.y = __builtin_amdgcn_perm(u[3], u[2], 0x07060302u);
                    int off = (w * 2 + nt) * 512 + (mt * 2 + (quad >> 1)) * 128 +
                              l15 * 8 + (quad & 1) * 4;
                    *(uint2*)&Ps[off] = pk;
                }
            }

            bf16x8 pf0 = *(const bf16x8*)&Ps[(w * 2 + 0) * 512 + lane * 8];
            bf16x8 pf1 = *(const bf16x8*)&Ps[(w * 2 + 1) * 512 + lane * 8];
            lsum[0] = __builtin_amdgcn_mfma_f32_16x16x32_bf16(pf0, ones, lsum[0], 0, 0, 0);
            lsum[1] = __builtin_amdgcn_mfma_f32_16x16x32_bf16(pf1, ones, lsum[1], 0, 0, 0);
            #pragma unroll
            for (int dt = 0; dt < 4; dt++) {
                bf16x8 vf = *(const bf16x8*)&Vs[(dt * 4 + r) * 512 + lane * 8];
                O[0][dt] = __builtin_amdgcn_mfma_f32_16x16x32_bf16(pf0, vf, O[0][dt], 0, 0, 0);
                O[1][dt] = __builtin_amdgcn_mfma_f32_16x16x32_bf16(pf1, vf, O[1][dt], 0, 0, 0);
            }
        }
    }

    const size_t srow = (size_t)(b * S_LEN + r0 + w * 32);
    #pragma unroll
    for (int rt = 0; rt < 2; rt++) {
        #pragma unroll
        for (int reg = 0; reg < 4; reg++) {
            float li = 1.0f / lsum[rt][reg];
            size_t rowoff = (srow + rt * 16 + quad * 4 + reg) * DMODEL + h * HD + l15;
            #pragma unroll
            for (int dt = 0; dt < 4; dt++)
                ctxb[rowoff + dt * 16] = f2bf_rne(O[rt][dt][reg] * li);
        }
    }
}

// ---------------------------------------------------------------------------
// Kernel 3: output projection v4, 8-way K-split.  512 blocks x 512 thr.
// ---------------------------------------------------------------------------
__global__ __launch_bounds__(512) void out_proj_mfma(
    const unsigned short* __restrict__ ctxb,
    const unsigned short* __restrict__ WfT,
    const float* __restrict__ bfb,
    float* __restrict__ out)
{
    __shared__ float Red[8 * 1024];   // [wave][lane][j*4+reg], 32 KB

    const int tid = threadIdx.x;
    const int lane = tid & 63, w = tid >> 6;    // w 0..7
    const int quad = lane >> 4, l15 = lane & 15;
    const int m0 = blockIdx.x * 16;

    const unsigned short* pA = ctxb + (size_t)(m0 + l15) * DMODEL + w * 128 + quad * 8;
    const unsigned short* pB = WfT + (size_t)l15 * DMODEL + w * 128 + quad * 8;

    f32x4 acc[4];
    #pragma unroll
    for (int j = 0; j < 4; j++)
        #pragma unroll
        for (int c = 0; c < 4; c++) acc[j][c] = 0.f;

    #pragma unroll
    for (int k0 = 0; k0 < 128; k0 += 32) {
        bf16x8 af = *(const bf16x8*)(pA + k0);
        #pragma unroll
        for (int j = 0; j < 4; j++) {
            bf16x8 bfr = *(const bf16x8*)(pB + (size_t)j * 16 * DMODEL + k0);
            acc[j] = __builtin_amdgcn_mfma_f32_16x16x32_bf16(af, bfr, acc[j], 0, 0, 0);
        }
    }

    #pragma unroll
    for (int j = 0; j < 4; j++)
        #pragma unroll
        for (int reg = 0; reg < 4; reg++)
            Red[w * 1024 + lane * 16 + j * 4 + reg] = acc[j][reg];
    __syncthreads();

    const int row = tid >> 5;          // 0..15
    const int c0  = (tid & 31) * 2;    // 0..62
    float2 o;
    float* op = &o.x;
    #pragma unroll
    for (int cc = 0; cc < 2; cc++) {
        int col = c0 + cc;
        int idx = ((row >> 2) * 16 + (col & 15)) * 16 + (col >> 4) * 4 + (row & 3);
        float s = 0.f;
        #pragma unroll
        for (int wv = 0; wv < 8; wv++) s += Red[wv * 1024 + idx];
        op[cc] = s + bfb[col];
    }
    *(float2*)(out + (size_t)(m0 + row) * HD + c0) = o;
}

// ---------------------------------------------------------------------------
extern "C" void kernel_launch(void* const* d_in, const int* in_sizes, int n_in,
                              void* d_out, int out_size, void* d_ws, size_t ws_size,
                              hipStream_t stream)
{
    (void)in_sizes; (void)n_in; (void)out_size; (void)ws_size;
    const float* x  = (const float*)d_in[0];
    const float* Wq = (const float*)d_in[1];
    const float* bq = (const float*)d_in[2];
    const float* Wk = (const float*)d_in[3];
    const float* bk = (const float*)d_in[4];
    const float* Wv = (const float*)d_in[5];
    const float* bv = (const float*)d_in[6];
    const float* Wf = (const float*)d_in[7];
    const float* bf = (const float*)d_in[8];
    float* out = (float*)d_out;

    char* wsb = (char*)d_ws;
    unsigned short* xb   = (unsigned short*)wsb;            // 16 MB, dead after qkv
    unsigned short* ctxb = (unsigned short*)wsb;            // reuses xb region
    unsigned short* WT   = xb + (size_t)M_TOT * DMODEL;     // 3x2 MB + WfT
    unsigned short* WfT  = WT + (size_t)3 * DMODEL * DMODEL;
    unsigned short* Qb   = (unsigned short*)(wsb + (size_t)32 * 1024 * 1024);
    unsigned short* Kb   = Qb + (size_t)M_TOT * DMODEL;
    unsigned short* Vtb  = Kb + (size_t)M_TOT * DMODEL;

    cvt_fused<<<dim3(16, 16, 5), 256, 0, stream>>>(x, Wq, Wk, Wv, Wf, xb, WT);
    qkv_gemm_mfma<<<dim3(768), 512, 0, stream>>>(xb, WT, bq, bk, bv, Qb, Kb, Vtb);
    flash_attn_mfma<<<dim3(S_LEN / 128, NH, BATCH), 256, 0, stream>>>(Qb, Kb, Vtb, ctxb);
    out_proj_mfma<<<dim3(M_TOT / 16), 512, 0, stream>>>(ctxb, WfT, bf, out);
}

// Round 3
// 268.631 us; speedup vs baseline: 1.0909x; 1.0909x over previous
//
#include <hip/hip_runtime.h>
#include <math.h>

#define S_LEN 2048
#define NH 16
#define HD 64
#define DMODEL 1024
#define BATCH 4
#define M_TOT (BATCH * S_LEN)   // 8192

typedef __attribute__((ext_vector_type(8))) short bf16x8;
typedef __attribute__((ext_vector_type(4))) float f32x4;

#define CK 0.18033688f   // (1/sqrt(64)) * log2(e), folded into Q at projection

__device__ __forceinline__ unsigned short f2bf_rne(float f) {
    unsigned u = __float_as_uint(f);
    u += 0x7fffu + ((u >> 16) & 1u);
    return (unsigned short)(u >> 16);
}

__device__ __forceinline__ void gld16(unsigned short* lds, const unsigned short* g) {
    __builtin_amdgcn_global_load_lds(
        (const __attribute__((address_space(1))) void*)g,
        (__attribute__((address_space(3))) void*)lds, 16, 0, 0);
}

// ---------------------------------------------------------------------------
// cvt_fused: one dispatch for all input conversion.
// z=0..2: Wq/Wk/Wv [k][n] fp32 -> WT [n][k] bf16 (64x64 transpose tiles)
// z=3:    Wf (1024x64) -> WfT [64][1024]   (only blockIdx.x==0 active)
// z=4:    x fp32 -> bf16 (256 blocks x 32 float4/thread)
// ---------------------------------------------------------------------------
__global__ __launch_bounds__(256) void cvt_fused(
    const float* __restrict__ x,
    const float* __restrict__ Wq, const float* __restrict__ Wk,
    const float* __restrict__ Wv, const float* __restrict__ Wf,
    unsigned short* __restrict__ xb, unsigned short* __restrict__ WT)
{
    const int z = blockIdx.z;
    const int tid = threadIdx.x;

    if (z < 4) {
        if (z == 3 && blockIdx.x > 0) return;
        const float* W = (z == 0) ? Wq : (z == 1) ? Wk : (z == 2) ? Wv : Wf;
        const int ncol = (z == 3) ? 64 : DMODEL;
        unsigned short* out = WT + (size_t)z * DMODEL * DMODEL;

        __shared__ float Lt[64][65];
        const int r0 = blockIdx.y * 64;
        const int c0 = blockIdx.x * 64;

        #pragma unroll
        for (int p = 0; p < 4; p++) {
            int row = (tid >> 4) + p * 16;
            int c4 = (tid & 15) * 4;
            float4 v = *(const float4*)(W + (size_t)(r0 + row) * ncol + c0 + c4);
            Lt[row][c4 + 0] = v.x; Lt[row][c4 + 1] = v.y;
            Lt[row][c4 + 2] = v.z; Lt[row][c4 + 3] = v.w;
        }
        __syncthreads();
        #pragma unroll
        for (int p = 0; p < 4; p++) {
            int nr = (tid >> 4) + p * 16;
            int kc = (tid & 15) * 4;
            unsigned short t[4];
            #pragma unroll
            for (int j = 0; j < 4; j++) t[j] = f2bf_rne(Lt[kc + j][nr]);
            *(uint2*)(out + (size_t)(c0 + nr) * DMODEL + r0 + kc) = *(uint2*)t;
        }
    } else {
        const int gtid = (blockIdx.y * 16 + blockIdx.x) * 256 + tid;
        #pragma unroll
        for (int it = 0; it < 8; it++) {
            #pragma unroll
            for (int k = 0; k < 4; k++) {
                size_t i = ((size_t)((it * 4 + k) * 65536) + gtid) * 4;
                float4 v = *(const float4*)(x + i);
                unsigned short t[4];
                t[0] = f2bf_rne(v.x); t[1] = f2bf_rne(v.y);
                t[2] = f2bf_rne(v.z); t[3] = f2bf_rne(v.w);
                *(uint2*)(xb + i) = *(uint2*)t;
            }
        }
    }
}

// ---------------------------------------------------------------------------
// Kernel 1 (R15): FUSED QKV projection.  One block owns (256 seq rows x
// 64 oc) and computes Q, K AND V for that tile: the x-tile is staged into
// LDS ONCE and reused by all three weight streams.
//   R0-R2 post-mortem: schedule changes (dbuf, counted vmcnt) were null;
//   the invariant bottleneck tracks bytes staged via global_load_lds
//   (R0: 1.18 GB total).  Fusing z cuts staged bytes 2.6x (459 MB) and
//   raises FLOP/staged-byte from 64 to 112.
//   Geometry: 512 blocks (32 rb x 16 ocb) = 2 balanced rounds/CU.
//   512 threads = 8 waves; each wave owns 32 seq rows x 64 oc x 3 z:
//   acc[3][4][2] = 96 VGPR.  LDS: 2 x (24 KB W + 32 KB x) = 112 KB.
//   Schedule: minimal safe dbuf -- __syncthreads (full drain) once per
//   K-step, stage(t+1) issued right after it so loads cover under compute.
//   Chunk layout / fragment reads / operand order (z==2 swapped for V^T)
//   / epilogues carried over verbatim from the R0-verified kernel.
// ---------------------------------------------------------------------------
__global__ __launch_bounds__(512) void qkv_fused_mfma(
    const unsigned short* __restrict__ xb,
    const unsigned short* __restrict__ WT,
    const float* __restrict__ bq, const float* __restrict__ bk,
    const float* __restrict__ bv,
    unsigned short* __restrict__ Qb, unsigned short* __restrict__ Kb,
    unsigned short* __restrict__ Vtb)
{
    // chunk = 512 shorts = 16 rows x 32 K (R0 convention).
    // W: 3 z x 4 oc16-groups x 2 K-slices = 24 chunks; x: 16 grp x 2 = 32.
    __shared__ __align__(16) unsigned short Ws[2][24 * 512];   // 2 x 24 KB
    __shared__ __align__(16) unsigned short Bs[2][32 * 512];   // 2 x 32 KB

    // ---- XCD swizzle: lin%8 = XCD; XCD k owns rb 4k..4k+3 for all ocb ----
    const int lin = blockIdx.x;          // 0..511
    const int xcd = lin & 7;
    const int s   = lin >> 3;            // 0..63
    const int rb  = xcd * 4 + (s & 3);   // 0..31  (256-row tiles)
    const int ocb = s >> 2;              // 0..15  (64-oc tiles)

    const int tid = threadIdx.x;
    const int lane = tid & 63, w = tid >> 6;        // w 0..7
    const int quad = lane >> 4, l15 = lane & 15;

    const int R0  = rb * 256;
    const int OC0 = ocb * 64;

    // stage sources.  Wave w stages, for each z, the chunk (i = w>>1,
    // sl = w&1) -> dest chunk index z*8 + w (since i*2+sl == w).
    const unsigned short* gW0 = WT +
        (size_t)(OC0 + (w >> 1) * 16 + l15) * DMODEL + (w & 1) * 32 + quad * 8;
    const unsigned short* gW1 = gW0 + (size_t)DMODEL * DMODEL;
    const unsigned short* gW2 = gW1 + (size_t)DMODEL * DMODEL;
    // x rows: wave w stages 16-row groups w (rows R0+w*16..) and w+8 (+128)
    const unsigned short* gB0 = xb + (size_t)(R0 + w * 16 + l15) * DMODEL + quad * 8;
    const unsigned short* gB1 = gB0 + (size_t)128 * DMODEL;

    f32x4 acc[3][4][2];
    #pragma unroll
    for (int z = 0; z < 3; z++)
        #pragma unroll
        for (int i = 0; i < 4; i++)
            #pragma unroll
            for (int j = 0; j < 2; j++)
                #pragma unroll
                for (int c = 0; c < 4; c++) acc[z][i][j][c] = 0.f;

    // 7 gld16 per wave per stage: 3 W chunks (one per z) + 4 x chunks
#define QKV_STAGE(BUF, K)  do {                                        \
        gld16(Ws[BUF] + (0 * 8 + w) * 512, gW0 + (K));                 \
        gld16(Ws[BUF] + (1 * 8 + w) * 512, gW1 + (K));                 \
        gld16(Ws[BUF] + (2 * 8 + w) * 512, gW2 + (K));                 \
        gld16(Bs[BUF] + ((w + 0) * 2 + 0) * 512, gB0 + (K));           \
        gld16(Bs[BUF] + ((w + 0) * 2 + 1) * 512, gB0 + (K) + 32);      \
        gld16(Bs[BUF] + ((w + 8) * 2 + 0) * 512, gB1 + (K));           \
        gld16(Bs[BUF] + ((w + 8) * 2 + 1) * 512, gB1 + (K) + 32);      \
    } while (0)

    QKV_STAGE(0, 0);

    for (int t = 0; t < 16; ++t) {
        const int cur = t & 1;
        // full drain + barrier: stage(t) landed (issued one compute-phase
        // ago) and all waves are done reading the buffer stage(t+1) writes.
        __syncthreads();
        if (t < 15) {
            if (cur == 0) QKV_STAGE(1, (t + 1) * 64);
            else          QKV_STAGE(0, (t + 1) * 64);
        }

        const unsigned short* Wb = Ws[cur];
        const unsigned short* Bb = Bs[cur];

        #pragma unroll
        for (int sl = 0; sl < 2; sl++) {
            bf16x8 bfr[2];
            #pragma unroll
            for (int j = 0; j < 2; j++)
                bfr[j] = *(const bf16x8*)&Bb[((2 * w + j) * 2 + sl) * 512 + lane * 8];
            #pragma unroll
            for (int z = 0; z < 3; z++) {
                bf16x8 af[4];
                #pragma unroll
                for (int i = 0; i < 4; i++)
                    af[i] = *(const bf16x8*)&Wb[(z * 8 + i * 2 + sl) * 512 + lane * 8];
                if (z != 2) {
                    #pragma unroll
                    for (int i = 0; i < 4; i++)
                        #pragma unroll
                        for (int j = 0; j < 2; j++)
                            acc[z][i][j] = __builtin_amdgcn_mfma_f32_16x16x32_bf16(
                                af[i], bfr[j], acc[z][i][j], 0, 0, 0);
                } else {
                    #pragma unroll
                    for (int i = 0; i < 4; i++)
                        #pragma unroll
                        for (int j = 0; j < 2; j++)
                            acc[2][i][j] = __builtin_amdgcn_mfma_f32_16x16x32_bf16(
                                bfr[j], af[i], acc[2][i][j], 0, 0, 0);
                }
            }
        }
    }
#undef QKV_STAGE

    // ---- epilogue: Q and K (rows = oc via quad*4+reg, cols = seq via l15)
    #pragma unroll
    for (int z = 0; z < 2; z++) {
        unsigned short* out = (z == 0) ? Qb : Kb;
        const float* bias = (z == 0) ? bq : bk;
        const float qs = (z == 0) ? CK : 1.0f;
        #pragma unroll
        for (int i = 0; i < 4; i++) {
            int oc = OC0 + i * 16 + quad * 4;
            float4 bv4 = *(const float4*)&bias[oc];
            #pragma unroll
            for (int j = 0; j < 2; j++) {
                int row = R0 + w * 32 + j * 16 + l15;
                unsigned short t4[4];
                t4[0] = f2bf_rne((acc[z][i][j][0] + bv4.x) * qs);
                t4[1] = f2bf_rne((acc[z][i][j][1] + bv4.y) * qs);
                t4[2] = f2bf_rne((acc[z][i][j][2] + bv4.z) * qs);
                t4[3] = f2bf_rne((acc[z][i][j][3] + bv4.w) * qs);
                *(uint2*)(out + (size_t)row * DMODEL + oc) = *(uint2*)t4;
            }
        }
    }
    // ---- epilogue: V (swapped operands: rows = seq via quad*4+reg,
    //      cols = oc via l15) -> transposed store [B,H,64,S]
    {
        const int b = R0 >> 11;                 // 256-row tiles never cross batch
        const int sbase = (R0 & 2047) + w * 32;
        #pragma unroll
        for (int i = 0; i < 4; i++) {
            int oc = OC0 + i * 16 + l15;
            float bvv = bv[oc];
            #pragma unroll
            for (int j = 0; j < 2; j++) {
                int sq = sbase + j * 16 + quad * 4;
                unsigned short t4[4];
                t4[0] = f2bf_rne(acc[2][i][j][0] + bvv);
                t4[1] = f2bf_rne(acc[2][i][j][1] + bvv);
                t4[2] = f2bf_rne(acc[2][i][j][2] + bvv);
                t4[3] = f2bf_rne(acc[2][i][j][3] + bvv);
                *(uint2*)(Vtb + (size_t)(b * DMODEL + oc) * S_LEN + sq) = *(uint2*)t4;
            }
        }
    }
}

// ---------------------------------------------------------------------------
// Kernel 2: flash attention — R8 structure (measured optimum) + XCD-AWARE
// SWIZZLE: all 16 q-tile blocks of one (b,h) map to the same XCD (bh%8), so
// that (b,h)'s K/V stream is fetched once per XCD instead of up to 8x.
// ---------------------------------------------------------------------------
__global__ __launch_bounds__(256, 4) void flash_attn_mfma(
    const unsigned short* __restrict__ Qg,   // [B*S,1024] bf16, pre-scaled by CK
    const unsigned short* __restrict__ Kg,   // [B*S,1024] bf16
    const unsigned short* __restrict__ Vtg,  // [B,H,64,S] bf16
    unsigned short* __restrict__ ctxb)       // [B*S,1024] bf16
{
    __shared__ __align__(16) unsigned short Ks[16 * 512];  // 16 KB
    __shared__ __align__(16) unsigned short Vs[16 * 512];  // 16 KB
    __shared__ __align__(16) unsigned short Ps[8 * 512];   //  8 KB

    const int tid  = threadIdx.x;
    const int lane = tid & 63, w = tid >> 6;
    const int quad = lane >> 4, l15 = lane & 15;

    // ---- XCD swizzle: lin -> (qblk, b, h) with bh%8 == lin%8 ----
    const int lin = blockIdx.x + 16 * (blockIdx.y + 16 * blockIdx.z);  // 0..1023
    const int xcd = lin & 7;
    const int s   = lin >> 3;              // 0..127
    const int bh  = xcd + 8 * (s >> 4);    // 0..63, bh%8 == xcd
    const int qblk = s & 15;
    const int b = bh >> 4, h = bh & 15;
    const int r0 = qblk * 128;

    bf16x8 qf[2][2];
    #pragma unroll
    for (int nt = 0; nt < 2; nt++)
        #pragma unroll
        for (int ds = 0; ds < 2; ds++)
            qf[nt][ds] = *(const bf16x8*)(Qg +
                (size_t)(b * S_LEN + r0 + w * 32 + nt * 16 + l15) * DMODEL +
                h * HD + ds * 32 + quad * 8);

    const unsigned short* gK = Kg + (size_t)(b * S_LEN + w * 16 + l15) * DMODEL + h * HD + quad * 8;
    const unsigned short* gV = Vtg + ((size_t)((b * NH + h) * HD + w * 16 + l15)) * S_LEN + quad * 8;

    f32x4 O[2][4], lsum[2];
    #pragma unroll
    for (int rt = 0; rt < 2; rt++) {
        #pragma unroll
        for (int c = 0; c < 4; c++) lsum[rt][c] = 0.f;
        #pragma unroll
        for (int dt = 0; dt < 4; dt++)
            #pragma unroll
            for (int c = 0; c < 4; c++) O[rt][dt][c] = 0.f;
    }

    f32x4 zero4;
    #pragma unroll
    for (int c = 0; c < 4; c++) zero4[c] = 0.f;
    bf16x8 ones;
    #pragma unroll
    for (int c = 0; c < 8; c++) ones[c] = (short)0x3F80;   // bf16 1.0

    for (int st = 0; st < S_LEN / 128; st++) {
        __syncthreads();
        gld16(Ks + ((w + 0) * 2 + 0) * 512, gK);
        gld16(Ks + ((w + 0) * 2 + 1) * 512, gK + 32);
        gld16(Ks + ((w + 4) * 2 + 0) * 512, gK + (size_t)64 * DMODEL);
        gld16(Ks + ((w + 4) * 2 + 1) * 512, gK + (size_t)64 * DMODEL + 32);
        gld16(Vs + (w * 4 + 0) * 512, gV);
        gld16(Vs + (w * 4 + 1) * 512, gV + 32);
        gld16(Vs + (w * 4 + 2) * 512, gV + 64);
        gld16(Vs + (w * 4 + 3) * 512, gV + 96);
        gK += (size_t)128 * DMODEL;
        gV += 128;
        __syncthreads();

        #pragma unroll
        for (int r = 0; r < 4; r++) {
            f32x4 sc[2][2];
            {
                bf16x8 kf0 = *(const bf16x8*)&Ks[((r * 2 + 0) * 2 + 0) * 512 + lane * 8];
                bf16x8 kf1 = *(const bf16x8*)&Ks[((r * 2 + 1) * 2 + 0) * 512 + lane * 8];
                sc[0][0] = __builtin_amdgcn_mfma_f32_16x16x32_bf16(kf0, qf[0][0], zero4, 0, 0, 0);
                sc[0][1] = __builtin_amdgcn_mfma_f32_16x16x32_bf16(kf0, qf[1][0], zero4, 0, 0, 0);
                sc[1][0] = __builtin_amdgcn_mfma_f32_16x16x32_bf16(kf1, qf[0][0], zero4, 0, 0, 0);
                sc[1][1] = __builtin_amdgcn_mfma_f32_16x16x32_bf16(kf1, qf[1][0], zero4, 0, 0, 0);
                kf0 = *(const bf16x8*)&Ks[((r * 2 + 0) * 2 + 1) * 512 + lane * 8];
                kf1 = *(const bf16x8*)&Ks[((r * 2 + 1) * 2 + 1) * 512 + lane * 8];
                sc[0][0] = __builtin_amdgcn_mfma_f32_16x16x32_bf16(kf0, qf[0][1], sc[0][0], 0, 0, 0);
                sc[0][1] = __builtin_amdgcn_mfma_f32_16x16x32_bf16(kf0, qf[1][1], sc[0][1], 0, 0, 0);
                sc[1][0] = __builtin_amdgcn_mfma_f32_16x16x32_bf16(kf1, qf[0][1], sc[1][0], 0, 0, 0);
                sc[1][1] = __builtin_amdgcn_mfma_f32_16x16x32_bf16(kf1, qf[1][1], sc[1][1], 0, 0, 0);
            }

            #pragma unroll
            for (int nt = 0; nt < 2; nt++) {
                #pragma unroll
                for (int mt = 0; mt < 2; mt++) {
                    unsigned u[4];
                    #pragma unroll
                    for (int c = 0; c < 4; c++)
                        u[c] = __float_as_uint(__builtin_amdgcn_exp2f(sc[mt][nt][c]));
                    uint2 pk;
                    pk.x = __builtin_amdgcn_perm(u[1], u[0], 0x07060302u);
                    pk.y = __builtin_amdgcn_perm(u[3], u[2], 0x07060302u);
                    int off = (w * 2 + nt) * 512 + (mt * 2 + (quad >> 1)) * 128 +
                              l15 * 8 + (quad & 1) * 4;
                    *(uint2*)&Ps[off] = pk;
                }
            }

            bf16x8 pf0 = *(const bf16x8*)&Ps[(w * 2 + 0) * 512 + lane * 8];
            bf16x8 pf1 = *(const bf16x8*)&Ps[(w * 2 + 1) * 512 + lane * 8];
            lsum[0] = __builtin_amdgcn_mfma_f32_16x16x32_bf16(pf0, ones, lsum[0], 0, 0, 0);
            lsum[1] = __builtin_amdgcn_mfma_f32_16x16x32_bf16(pf1, ones, lsum[1], 0, 0, 0);
            #pragma unroll
            for (int dt = 0; dt < 4; dt++) {
                bf16x8 vf = *(const bf16x8*)&Vs[(dt * 4 + r) * 512 + lane * 8];
                O[0][dt] = __builtin_amdgcn_mfma_f32_16x16x32_bf16(pf0, vf, O[0][dt], 0, 0, 0);
                O[1][dt] = __builtin_amdgcn_mfma_f32_16x16x32_bf16(pf1, vf, O[1][dt], 0, 0, 0);
            }
        }
    }

    const size_t srow = (size_t)(b * S_LEN + r0 + w * 32);
    #pragma unroll
    for (int rt = 0; rt < 2; rt++) {
        #pragma unroll
        for (int reg = 0; reg < 4; reg++) {
            float li = 1.0f / lsum[rt][reg];
            size_t rowoff = (srow + rt * 16 + quad * 4 + reg) * DMODEL + h * HD + l15;
            #pragma unroll
            for (int dt = 0; dt < 4; dt++)
                ctxb[rowoff + dt * 16] = f2bf_rne(O[rt][dt][reg] * li);
        }
    }
}

// ---------------------------------------------------------------------------
// Kernel 3: output projection v4, 8-way K-split.  512 blocks x 512 thr.
// ---------------------------------------------------------------------------
__global__ __launch_bounds__(512) void out_proj_mfma(
    const unsigned short* __restrict__ ctxb,
    const unsigned short* __restrict__ WfT,
    const float* __restrict__ bfb,
    float* __restrict__ out)
{
    __shared__ float Red[8 * 1024];   // [wave][lane][j*4+reg], 32 KB

    const int tid = threadIdx.x;
    const int lane = tid & 63, w = tid >> 6;    // w 0..7
    const int quad = lane >> 4, l15 = lane & 15;
    const int m0 = blockIdx.x * 16;

    const unsigned short* pA = ctxb + (size_t)(m0 + l15) * DMODEL + w * 128 + quad * 8;
    const unsigned short* pB = WfT + (size_t)l15 * DMODEL + w * 128 + quad * 8;

    f32x4 acc[4];
    #pragma unroll
    for (int j = 0; j < 4; j++)
        #pragma unroll
        for (int c = 0; c < 4; c++) acc[j][c] = 0.f;

    #pragma unroll
    for (int k0 = 0; k0 < 128; k0 += 32) {
        bf16x8 af = *(const bf16x8*)(pA + k0);
        #pragma unroll
        for (int j = 0; j < 4; j++) {
            bf16x8 bfr = *(const bf16x8*)(pB + (size_t)j * 16 * DMODEL + k0);
            acc[j] = __builtin_amdgcn_mfma_f32_16x16x32_bf16(af, bfr, acc[j], 0, 0, 0);
        }
    }

    #pragma unroll
    for (int j = 0; j < 4; j++)
        #pragma unroll
        for (int reg = 0; reg < 4; reg++)
            Red[w * 1024 + lane * 16 + j * 4 + reg] = acc[j][reg];
    __syncthreads();

    const int row = tid >> 5;          // 0..15
    const int c0  = (tid & 31) * 2;    // 0..62
    float2 o;
    float* op = &o.x;
    #pragma unroll
    for (int cc = 0; cc < 2; cc++) {
        int col = c0 + cc;
        int idx = ((row >> 2) * 16 + (col & 15)) * 16 + (col >> 4) * 4 + (row & 3);
        float s = 0.f;
        #pragma unroll
        for (int wv = 0; wv < 8; wv++) s += Red[wv * 1024 + idx];
        op[cc] = s + bfb[col];
    }
    *(float2*)(out + (size_t)(m0 + row) * HD + c0) = o;
}

// ---------------------------------------------------------------------------
extern "C" void kernel_launch(void* const* d_in, const int* in_sizes, int n_in,
                              void* d_out, int out_size, void* d_ws, size_t ws_size,
                              hipStream_t stream)
{
    (void)in_sizes; (void)n_in; (void)out_size; (void)ws_size;
    const float* x  = (const float*)d_in[0];
    const float* Wq = (const float*)d_in[1];
    const float* bq = (const float*)d_in[2];
    const float* Wk = (const float*)d_in[3];
    const float* bk = (const float*)d_in[4];
    const float* Wv = (const float*)d_in[5];
    const float* bv = (const float*)d_in[6];
    const float* Wf = (const float*)d_in[7];
    const float* bf = (const float*)d_in[8];
    float* out = (float*)d_out;

    char* wsb = (char*)d_ws;
    unsigned short* xb   = (unsigned short*)wsb;            // 16 MB, dead after qkv
    unsigned short* ctxb = (unsigned short*)wsb;            // reuses xb region
    unsigned short* WT   = xb + (size_t)M_TOT * DMODEL;     // 3x2 MB + WfT
    unsigned short* WfT  = WT + (size_t)3 * DMODEL * DMODEL;
    unsigned short* Qb   = (unsigned short*)(wsb + (size_t)32 * 1024 * 1024);
    unsigned short* Kb   = Qb + (size_t)M_TOT * DMODEL;
    unsigned short* Vtb  = Kb + (size_t)M_TOT * DMODEL;

    cvt_fused<<<dim3(16, 16, 5), 256, 0, stream>>>(x, Wq, Wk, Wv, Wf, xb, WT);
    qkv_fused_mfma<<<dim3(512), 512, 0, stream>>>(xb, WT, bq, bk, bv, Qb, Kb, Vtb);
    flash_attn_mfma<<<dim3(S_LEN / 128, NH, BATCH), 256, 0, stream>>>(Qb, Kb, Vtb, ctxb);
    out_proj_mfma<<<dim3(M_TOT / 16), 512, 0, stream>>>(ctxb, WfT, bf, out);
}

// Round 4
// 257.287 us; speedup vs baseline: 1.1390x; 1.0441x over previous
//
#include <hip/hip_runtime.h>
#include <math.h>

#define S_LEN 2048
#define NH 16
#define HD 64
#define DMODEL 1024
#define BATCH 4
#define M_TOT (BATCH * S_LEN)   // 8192

typedef __attribute__((ext_vector_type(8))) short bf16x8;
typedef __attribute__((ext_vector_type(4))) float f32x4;

#define CK 0.18033688f   // (1/sqrt(64)) * log2(e), folded into Q at projection

__device__ __forceinline__ unsigned short f2bf_rne(float f) {
    unsigned u = __float_as_uint(f);
    u += 0x7fffu + ((u >> 16) & 1u);
    return (unsigned short)(u >> 16);
}

__device__ __forceinline__ void gld16(unsigned short* lds, const unsigned short* g) {
    __builtin_amdgcn_global_load_lds(
        (const __attribute__((address_space(1))) void*)g,
        (__attribute__((address_space(3))) void*)lds, 16, 0, 0);
}

// ---------------------------------------------------------------------------
// cvt_fused: one dispatch for all input conversion.
// z=0..2: Wq/Wk/Wv [k][n] fp32 -> WT [n][k] bf16 (64x64 transpose tiles)
// z=3:    Wf (1024x64) -> WfT [64][1024]   (only blockIdx.x==0 active)
// z=4:    x fp32 -> bf16 (256 blocks x 32 float4/thread)
// ---------------------------------------------------------------------------
__global__ __launch_bounds__(256) void cvt_fused(
    const float* __restrict__ x,
    const float* __restrict__ Wq, const float* __restrict__ Wk,
    const float* __restrict__ Wv, const float* __restrict__ Wf,
    unsigned short* __restrict__ xb, unsigned short* __restrict__ WT)
{
    const int z = blockIdx.z;
    const int tid = threadIdx.x;

    if (z < 4) {
        if (z == 3 && blockIdx.x > 0) return;
        const float* W = (z == 0) ? Wq : (z == 1) ? Wk : (z == 2) ? Wv : Wf;
        const int ncol = (z == 3) ? 64 : DMODEL;
        unsigned short* out = WT + (size_t)z * DMODEL * DMODEL;

        __shared__ float Lt[64][65];
        const int r0 = blockIdx.y * 64;
        const int c0 = blockIdx.x * 64;

        #pragma unroll
        for (int p = 0; p < 4; p++) {
            int row = (tid >> 4) + p * 16;
            int c4 = (tid & 15) * 4;
            float4 v = *(const float4*)(W + (size_t)(r0 + row) * ncol + c0 + c4);
            Lt[row][c4 + 0] = v.x; Lt[row][c4 + 1] = v.y;
            Lt[row][c4 + 2] = v.z; Lt[row][c4 + 3] = v.w;
        }
        __syncthreads();
        #pragma unroll
        for (int p = 0; p < 4; p++) {
            int nr = (tid >> 4) + p * 16;
            int kc = (tid & 15) * 4;
            unsigned short t[4];
            #pragma unroll
            for (int j = 0; j < 4; j++) t[j] = f2bf_rne(Lt[kc + j][nr]);
            *(uint2*)(out + (size_t)(c0 + nr) * DMODEL + r0 + kc) = *(uint2*)t;
        }
    } else {
        const int gtid = (blockIdx.y * 16 + blockIdx.x) * 256 + tid;
        #pragma unroll
        for (int it = 0; it < 8; it++) {
            #pragma unroll
            for (int k = 0; k < 4; k++) {
                size_t i = ((size_t)((it * 4 + k) * 65536) + gtid) * 4;
                float4 v = *(const float4*)(x + i);
                unsigned short t[4];
                t[0] = f2bf_rne(v.x); t[1] = f2bf_rne(v.y);
                t[2] = f2bf_rne(v.z); t[3] = f2bf_rne(v.w);
                *(uint2*)(xb + i) = *(uint2*)t;
            }
        }
    }
}

// ---------------------------------------------------------------------------
// Kernel 1 (R15, kept): FUSED QKV projection.  One block owns (256 seq rows
// x 64 oc) and computes Q, K AND V for that tile: x staged ONCE, reused 3x.
// R3 verified: steady-state <= 90 us (vs 110 split).  NOTE: one rocprof
// replay showed a 31 ms outlier dispatch (FETCH 41 MB @ 3 GB/s, MfmaUtil
// 4.8%) inconsistent with wall-clock 268 us -- treated as replay artifact,
// monitoring.
// ---------------------------------------------------------------------------
__global__ __launch_bounds__(512) void qkv_fused_mfma(
    const unsigned short* __restrict__ xb,
    const unsigned short* __restrict__ WT,
    const float* __restrict__ bq, const float* __restrict__ bk,
    const float* __restrict__ bv,
    unsigned short* __restrict__ Qb, unsigned short* __restrict__ Kb,
    unsigned short* __restrict__ Vtb)
{
    __shared__ __align__(16) unsigned short Ws[2][24 * 512];   // 2 x 24 KB
    __shared__ __align__(16) unsigned short Bs[2][32 * 512];   // 2 x 32 KB

    const int lin = blockIdx.x;          // 0..511
    const int xcd = lin & 7;
    const int s   = lin >> 3;            // 0..63
    const int rb  = xcd * 4 + (s & 3);   // 0..31  (256-row tiles)
    const int ocb = s >> 2;              // 0..15  (64-oc tiles)

    const int tid = threadIdx.x;
    const int lane = tid & 63, w = tid >> 6;        // w 0..7
    const int quad = lane >> 4, l15 = lane & 15;

    const int R0  = rb * 256;
    const int OC0 = ocb * 64;

    const unsigned short* gW0 = WT +
        (size_t)(OC0 + (w >> 1) * 16 + l15) * DMODEL + (w & 1) * 32 + quad * 8;
    const unsigned short* gW1 = gW0 + (size_t)DMODEL * DMODEL;
    const unsigned short* gW2 = gW1 + (size_t)DMODEL * DMODEL;
    const unsigned short* gB0 = xb + (size_t)(R0 + w * 16 + l15) * DMODEL + quad * 8;
    const unsigned short* gB1 = gB0 + (size_t)128 * DMODEL;

    f32x4 acc[3][4][2];
    #pragma unroll
    for (int z = 0; z < 3; z++)
        #pragma unroll
        for (int i = 0; i < 4; i++)
            #pragma unroll
            for (int j = 0; j < 2; j++)
                #pragma unroll
                for (int c = 0; c < 4; c++) acc[z][i][j][c] = 0.f;

#define QKV_STAGE(BUF, K)  do {                                        \
        gld16(Ws[BUF] + (0 * 8 + w) * 512, gW0 + (K));                 \
        gld16(Ws[BUF] + (1 * 8 + w) * 512, gW1 + (K));                 \
        gld16(Ws[BUF] + (2 * 8 + w) * 512, gW2 + (K));                 \
        gld16(Bs[BUF] + ((w + 0) * 2 + 0) * 512, gB0 + (K));           \
        gld16(Bs[BUF] + ((w + 0) * 2 + 1) * 512, gB0 + (K) + 32);      \
        gld16(Bs[BUF] + ((w + 8) * 2 + 0) * 512, gB1 + (K));           \
        gld16(Bs[BUF] + ((w + 8) * 2 + 1) * 512, gB1 + (K) + 32);      \
    } while (0)

    QKV_STAGE(0, 0);

    for (int t = 0; t < 16; ++t) {
        const int cur = t & 1;
        __syncthreads();
        if (t < 15) {
            if (cur == 0) QKV_STAGE(1, (t + 1) * 64);
            else          QKV_STAGE(0, (t + 1) * 64);
        }

        const unsigned short* Wb = Ws[cur];
        const unsigned short* Bb = Bs[cur];

        #pragma unroll
        for (int sl = 0; sl < 2; sl++) {
            bf16x8 bfr[2];
            #pragma unroll
            for (int j = 0; j < 2; j++)
                bfr[j] = *(const bf16x8*)&Bb[((2 * w + j) * 2 + sl) * 512 + lane * 8];
            #pragma unroll
            for (int z = 0; z < 3; z++) {
                bf16x8 af[4];
                #pragma unroll
                for (int i = 0; i < 4; i++)
                    af[i] = *(const bf16x8*)&Wb[(z * 8 + i * 2 + sl) * 512 + lane * 8];
                if (z != 2) {
                    #pragma unroll
                    for (int i = 0; i < 4; i++)
                        #pragma unroll
                        for (int j = 0; j < 2; j++)
                            acc[z][i][j] = __builtin_amdgcn_mfma_f32_16x16x32_bf16(
                                af[i], bfr[j], acc[z][i][j], 0, 0, 0);
                } else {
                    #pragma unroll
                    for (int i = 0; i < 4; i++)
                        #pragma unroll
                        for (int j = 0; j < 2; j++)
                            acc[2][i][j] = __builtin_amdgcn_mfma_f32_16x16x32_bf16(
                                bfr[j], af[i], acc[2][i][j], 0, 0, 0);
                }
            }
        }
    }
#undef QKV_STAGE

    #pragma unroll
    for (int z = 0; z < 2; z++) {
        unsigned short* out = (z == 0) ? Qb : Kb;
        const float* bias = (z == 0) ? bq : bk;
        const float qs = (z == 0) ? CK : 1.0f;
        #pragma unroll
        for (int i = 0; i < 4; i++) {
            int oc = OC0 + i * 16 + quad * 4;
            float4 bv4 = *(const float4*)&bias[oc];
            #pragma unroll
            for (int j = 0; j < 2; j++) {
                int row = R0 + w * 32 + j * 16 + l15;
                unsigned short t4[4];
                t4[0] = f2bf_rne((acc[z][i][j][0] + bv4.x) * qs);
                t4[1] = f2bf_rne((acc[z][i][j][1] + bv4.y) * qs);
                t4[2] = f2bf_rne((acc[z][i][j][2] + bv4.z) * qs);
                t4[3] = f2bf_rne((acc[z][i][j][3] + bv4.w) * qs);
                *(uint2*)(out + (size_t)row * DMODEL + oc) = *(uint2*)t4;
            }
        }
    }
    {
        const int b = R0 >> 11;
        const int sbase = (R0 & 2047) + w * 32;
        #pragma unroll
        for (int i = 0; i < 4; i++) {
            int oc = OC0 + i * 16 + l15;
            float bvv = bv[oc];
            #pragma unroll
            for (int j = 0; j < 2; j++) {
                int sq = sbase + j * 16 + quad * 4;
                unsigned short t4[4];
                t4[0] = f2bf_rne(acc[2][i][j][0] + bvv);
                t4[1] = f2bf_rne(acc[2][i][j][1] + bvv);
                t4[2] = f2bf_rne(acc[2][i][j][2] + bvv);
                t4[3] = f2bf_rne(acc[2][i][j][3] + bvv);
                *(uint2*)(Vtb + (size_t)(b * DMODEL + oc) * S_LEN + sq) = *(uint2*)t4;
            }
        }
    }
}

// ---------------------------------------------------------------------------
// Kernel 2 (R16): flash attention, q-tile 256 rows x 8 waves (512 thr).
//   R3 counters: attn 92.5 us, nothing saturated (Mfma 35 / VALU 33 /
//   HBM 5.7 / occ 34) -- same staged-bytes regime qkv was in.  Doubling the
//   q-tile HALVES blocks -> K/V staged bytes 512->256 MB and halves the
//   barrier/drain count per FLOP.  Per-wave inner loop (r-loop, P-pack,
//   PV, epilogue) is verbatim from the verified R8 kernel; only staging
//   roles changed: waves 0-3 stage K (4 gld16), waves 4-7 stage V.
//   LDS 48 KB -> 2 blocks/CU fully resident (16 waves/CU).
// ---------------------------------------------------------------------------
__global__ __launch_bounds__(512, 4) void flash_attn_mfma(
    const unsigned short* __restrict__ Qg,   // [B*S,1024] bf16, pre-scaled by CK
    const unsigned short* __restrict__ Kg,   // [B*S,1024] bf16
    const unsigned short* __restrict__ Vtg,  // [B,H,64,S] bf16
    unsigned short* __restrict__ ctxb)       // [B*S,1024] bf16
{
    __shared__ __align__(16) unsigned short Ks[16 * 512];  // 16 KB
    __shared__ __align__(16) unsigned short Vs[16 * 512];  // 16 KB
    __shared__ __align__(16) unsigned short Ps[16 * 512];  // 16 KB

    const int tid  = threadIdx.x;
    const int lane = tid & 63, w = tid >> 6;   // w 0..7
    const int quad = lane >> 4, l15 = lane & 15;

    // ---- XCD swizzle: 512 blocks; all 8 q-blocks of (b,h) on XCD bh%8 ----
    const int lin = blockIdx.x;            // 0..511
    const int xcd = lin & 7;
    const int s   = lin >> 3;              // 0..63
    const int bh  = xcd + 8 * (s >> 3);    // 0..63, bh%8 == xcd
    const int qblk = s & 7;                // 0..7
    const int b = bh >> 4, h = bh & 15;
    const int r0 = qblk * 256;

    bf16x8 qf[2][2];
    #pragma unroll
    for (int nt = 0; nt < 2; nt++)
        #pragma unroll
        for (int ds = 0; ds < 2; ds++)
            qf[nt][ds] = *(const bf16x8*)(Qg +
                (size_t)(b * S_LEN + r0 + w * 32 + nt * 16 + l15) * DMODEL +
                h * HD + ds * 32 + quad * 8);

    // staging roles: waves 0-3 -> K rows [w*32, w*32+32); waves 4-7 -> V
    // d-groups [(w-4)*16, ...).  4 gld16 per wave per st.
    const int sw = w & 3;
    const unsigned short* gK = Kg +
        (size_t)(b * S_LEN + sw * 32 + l15) * DMODEL + h * HD + quad * 8;
    const unsigned short* gV = Vtg +
        ((size_t)(bh * HD + sw * 16 + l15)) * S_LEN + quad * 8;

    f32x4 O[2][4], lsum[2];
    #pragma unroll
    for (int rt = 0; rt < 2; rt++) {
        #pragma unroll
        for (int c = 0; c < 4; c++) lsum[rt][c] = 0.f;
        #pragma unroll
        for (int dt = 0; dt < 4; dt++)
            #pragma unroll
            for (int c = 0; c < 4; c++) O[rt][dt][c] = 0.f;
    }

    f32x4 zero4;
    #pragma unroll
    for (int c = 0; c < 4; c++) zero4[c] = 0.f;
    bf16x8 ones;
    #pragma unroll
    for (int c = 0; c < 8; c++) ones[c] = (short)0x3F80;   // bf16 1.0

    for (int st = 0; st < S_LEN / 128; st++) {
        __syncthreads();
        if (w < 4) {
            // K chunks (kgroup*2 + half): kgroups 2w, 2w+1; halves 0,1
            gld16(Ks + (w * 4 + 0) * 512, gK);
            gld16(Ks + (w * 4 + 1) * 512, gK + 32);
            gld16(Ks + (w * 4 + 2) * 512, gK + (size_t)16 * DMODEL);
            gld16(Ks + (w * 4 + 3) * 512, gK + (size_t)16 * DMODEL + 32);
            gK += (size_t)128 * DMODEL;
        } else {
            // V chunks (dgroup*4 + seq-quarter)
            gld16(Vs + (sw * 4 + 0) * 512, gV);
            gld16(Vs + (sw * 4 + 1) * 512, gV + 32);
            gld16(Vs + (sw * 4 + 2) * 512, gV + 64);
            gld16(Vs + (sw * 4 + 3) * 512, gV + 96);
            gV += 128;
        }
        __syncthreads();

        #pragma unroll
        for (int r = 0; r < 4; r++) {
            f32x4 sc[2][2];
            {
                bf16x8 kf0 = *(const bf16x8*)&Ks[((r * 2 + 0) * 2 + 0) * 512 + lane * 8];
                bf16x8 kf1 = *(const bf16x8*)&Ks[((r * 2 + 1) * 2 + 0) * 512 + lane * 8];
                sc[0][0] = __builtin_amdgcn_mfma_f32_16x16x32_bf16(kf0, qf[0][0], zero4, 0, 0, 0);
                sc[0][1] = __builtin_amdgcn_mfma_f32_16x16x32_bf16(kf0, qf[1][0], zero4, 0, 0, 0);
                sc[1][0] = __builtin_amdgcn_mfma_f32_16x16x32_bf16(kf1, qf[0][0], zero4, 0, 0, 0);
                sc[1][1] = __builtin_amdgcn_mfma_f32_16x16x32_bf16(kf1, qf[1][0], zero4, 0, 0, 0);
                kf0 = *(const bf16x8*)&Ks[((r * 2 + 0) * 2 + 1) * 512 + lane * 8];
                kf1 = *(const bf16x8*)&Ks[((r * 2 + 1) * 2 + 1) * 512 + lane * 8];
                sc[0][0] = __builtin_amdgcn_mfma_f32_16x16x32_bf16(kf0, qf[0][1], sc[0][0], 0, 0, 0);
                sc[0][1] = __builtin_amdgcn_mfma_f32_16x16x32_bf16(kf0, qf[1][1], sc[0][1], 0, 0, 0);
                sc[1][0] = __builtin_amdgcn_mfma_f32_16x16x32_bf16(kf1, qf[0][1], sc[1][0], 0, 0, 0);
                sc[1][1] = __builtin_amdgcn_mfma_f32_16x16x32_bf16(kf1, qf[1][1], sc[1][1], 0, 0, 0);
            }

            #pragma unroll
            for (int nt = 0; nt < 2; nt++) {
                #pragma unroll
                for (int mt = 0; mt < 2; mt++) {
                    unsigned u[4];
                    #pragma unroll
                    for (int c = 0; c < 4; c++)
                        u[c] = __float_as_uint(__builtin_amdgcn_exp2f(sc[mt][nt][c]));
                    uint2 pk;
                    pk.x = __builtin_amdgcn_perm(u[1], u[0], 0x07060302u);
                    pk.y = __builtin_amdgcn_perm(u[3], u[2], 0x07060302u);
                    int off = (w * 2 + nt) * 512 + (mt * 2 + (quad >> 1)) * 128 +
                              l15 * 8 + (quad & 1) * 4;
                    *(uint2*)&Ps[off] = pk;
                }
            }

            bf16x8 pf0 = *(const bf16x8*)&Ps[(w * 2 + 0) * 512 + lane * 8];
            bf16x8 pf1 = *(const bf16x8*)&Ps[(w * 2 + 1) * 512 + lane * 8];
            lsum[0] = __builtin_amdgcn_mfma_f32_16x16x32_bf16(pf0, ones, lsum[0], 0, 0, 0);
            lsum[1] = __builtin_amdgcn_mfma_f32_16x16x32_bf16(pf1, ones, lsum[1], 0, 0, 0);
            #pragma unroll
            for (int dt = 0; dt < 4; dt++) {
                bf16x8 vf = *(const bf16x8*)&Vs[(dt * 4 + r) * 512 + lane * 8];
                O[0][dt] = __builtin_amdgcn_mfma_f32_16x16x32_bf16(pf0, vf, O[0][dt], 0, 0, 0);
                O[1][dt] = __builtin_amdgcn_mfma_f32_16x16x32_bf16(pf1, vf, O[1][dt], 0, 0, 0);
            }
        }
    }

    const size_t srow = (size_t)(b * S_LEN + r0 + w * 32);
    #pragma unroll
    for (int rt = 0; rt < 2; rt++) {
        #pragma unroll
        for (int reg = 0; reg < 4; reg++) {
            float li = 1.0f / lsum[rt][reg];
            size_t rowoff = (srow + rt * 16 + quad * 4 + reg) * DMODEL + h * HD + l15;
            #pragma unroll
            for (int dt = 0; dt < 4; dt++)
                ctxb[rowoff + dt * 16] = f2bf_rne(O[rt][dt][reg] * li);
        }
    }
}

// ---------------------------------------------------------------------------
// Kernel 3: output projection v4, 8-way K-split.  512 blocks x 512 thr.
// ---------------------------------------------------------------------------
__global__ __launch_bounds__(512) void out_proj_mfma(
    const unsigned short* __restrict__ ctxb,
    const unsigned short* __restrict__ WfT,
    const float* __restrict__ bfb,
    float* __restrict__ out)
{
    __shared__ float Red[8 * 1024];   // [wave][lane][j*4+reg], 32 KB

    const int tid = threadIdx.x;
    const int lane = tid & 63, w = tid >> 6;    // w 0..7
    const int quad = lane >> 4, l15 = lane & 15;
    const int m0 = blockIdx.x * 16;

    const unsigned short* pA = ctxb + (size_t)(m0 + l15) * DMODEL + w * 128 + quad * 8;
    const unsigned short* pB = WfT + (size_t)l15 * DMODEL + w * 128 + quad * 8;

    f32x4 acc[4];
    #pragma unroll
    for (int j = 0; j < 4; j++)
        #pragma unroll
        for (int c = 0; c < 4; c++) acc[j][c] = 0.f;

    #pragma unroll
    for (int k0 = 0; k0 < 128; k0 += 32) {
        bf16x8 af = *(const bf16x8*)(pA + k0);
        #pragma unroll
        for (int j = 0; j < 4; j++) {
            bf16x8 bfr = *(const bf16x8*)(pB + (size_t)j * 16 * DMODEL + k0);
            acc[j] = __builtin_amdgcn_mfma_f32_16x16x32_bf16(af, bfr, acc[j], 0, 0, 0);
        }
    }

    #pragma unroll
    for (int j = 0; j < 4; j++)
        #pragma unroll
        for (int reg = 0; reg < 4; reg++)
            Red[w * 1024 + lane * 16 + j * 4 + reg] = acc[j][reg];
    __syncthreads();

    const int row = tid >> 5;          // 0..15
    const int c0  = (tid & 31) * 2;    // 0..62
    float2 o;
    float* op = &o.x;
    #pragma unroll
    for (int cc = 0; cc < 2; cc++) {
        int col = c0 + cc;
        int idx = ((row >> 2) * 16 + (col & 15)) * 16 + (col >> 4) * 4 + (row & 3);
        float s = 0.f;
        #pragma unroll
        for (int wv = 0; wv < 8; wv++) s += Red[wv * 1024 + idx];
        op[cc] = s + bfb[col];
    }
    *(float2*)(out + (size_t)(m0 + row) * HD + c0) = o;
}

// ---------------------------------------------------------------------------
extern "C" void kernel_launch(void* const* d_in, const int* in_sizes, int n_in,
                              void* d_out, int out_size, void* d_ws, size_t ws_size,
                              hipStream_t stream)
{
    (void)in_sizes; (void)n_in; (void)out_size; (void)ws_size;
    const float* x  = (const float*)d_in[0];
    const float* Wq = (const float*)d_in[1];
    const float* bq = (const float*)d_in[2];
    const float* Wk = (const float*)d_in[3];
    const float* bk = (const float*)d_in[4];
    const float* Wv = (const float*)d_in[5];
    const float* bv = (const float*)d_in[6];
    const float* Wf = (const float*)d_in[7];
    const float* bf = (const float*)d_in[8];
    float* out = (float*)d_out;

    char* wsb = (char*)d_ws;
    unsigned short* xb   = (unsigned short*)wsb;            // 16 MB, dead after qkv
    unsigned short* ctxb = (unsigned short*)wsb;            // reuses xb region
    unsigned short* WT   = xb + (size_t)M_TOT * DMODEL;     // 3x2 MB + WfT
    unsigned short* WfT  = WT + (size_t)3 * DMODEL * DMODEL;
    unsigned short* Qb   = (unsigned short*)(wsb + (size_t)32 * 1024 * 1024);
    unsigned short* Kb   = Qb + (size_t)M_TOT * DMODEL;
    unsigned short* Vtb  = Kb + (size_t)M_TOT * DMODEL;

    cvt_fused<<<dim3(16, 16, 5), 256, 0, stream>>>(x, Wq, Wk, Wv, Wf, xb, WT);
    qkv_fused_mfma<<<dim3(512), 512, 0, stream>>>(xb, WT, bq, bk, bv, Qb, Kb, Vtb);
    flash_attn_mfma<<<dim3(512), 512, 0, stream>>>(Qb, Kb, Vtb, ctxb);
    out_proj_mfma<<<dim3(M_TOT / 16), 512, 0, stream>>>(ctxb, WfT, bf, out);
}